// Round 1
// baseline (1154.306 us; speedup 1.0000x reference)
//
#include <hip/hip_runtime.h>

#define HIDDEN 4096
#define NKV 8
#define NH 32
#define HD 128
#define BATCH 2
#define SEQ 4096
#define ROWS (BATCH*SEQ)   // 8192

typedef short bf16x8 __attribute__((ext_vector_type(8)));
typedef float f32x4 __attribute__((ext_vector_type(4)));

static __device__ __forceinline__ float bf2f(unsigned short u) {
    union { unsigned int i; float f; } c; c.i = ((unsigned int)u) << 16; return c.f;
}
static __device__ __forceinline__ unsigned short f2bf(float x) {
    union { float f; unsigned int i; } c; c.f = x;
    unsigned int r = c.i + 0x7fffu + ((c.i >> 16) & 1u);
    return (unsigned short)(r >> 16);
}

static __device__ __forceinline__ void gl2lds16(const void* g, void* l) {
    __builtin_amdgcn_global_load_lds(
        (const __attribute__((address_space(1))) unsigned int*)g,
        (__attribute__((address_space(3))) unsigned int*)l, 16, 0, 0);
}

// ---------------------------------------------------------------- casts
__global__ __launch_bounds__(256)
void cast_kernel(const float* __restrict__ in, unsigned short* __restrict__ out, int n4) {
    int idx = blockIdx.x * blockDim.x + threadIdx.x;
    int stride = gridDim.x * blockDim.x;
    for (int i = idx; i < n4; i += stride) {
        float4 f = ((const float4*)in)[i];
        ushort4 o;
        o.x = f2bf(f.x); o.y = f2bf(f.y); o.z = f2bf(f.z); o.w = f2bf(f.w);
        ((ushort4*)out)[i] = o;
    }
}

// ---------------------------------------------------------------- generic GEMM: C = A @ B^T (+bias, act)
// A: [M,K] bf16 row-major (lda), B: [N,K] bf16 row-major (ldb)
// ACT: 0 = none, 1 = elu+1 ; OUT_BF16: 1 -> ushort out, 0 -> float out
template<int ACT, int OUT_BF16>
__global__ __launch_bounds__(256)
void gemm_bt(const unsigned short* __restrict__ A, int lda,
             const unsigned short* __restrict__ B, int ldb,
             const float* __restrict__ bias,
             void* __restrict__ Cout,
             int M, int N, int K)
{
    const int BK = 32;
    __shared__ unsigned short As[128 * BK];
    __shared__ unsigned short Bs[128 * BK];

    int nbx = N >> 7;
    int nwg = nbx * (M >> 7);
    int bid = blockIdx.x;
    int cpx = nwg >> 3;                 // nwg % 8 == 0 for all launches
    int wg = (bid & 7) * cpx + (bid >> 3);
    int bx = wg % nbx, by = wg / nbx;
    int rowBase = by << 7, colBase = bx << 7;

    int tid = threadIdx.x;
    int wave = tid >> 6, lane = tid & 63;
    int wr = wave >> 1, wc = wave & 1;

    f32x4 acc[4][4] = {};

    int sr = lane >> 2;              // staging row within 16-row group
    int sc = (lane & 3) * 8;         // staging col (elements)

    const unsigned short* Aw = A + (size_t)(rowBase + wave * 32 + sr) * lda + sc;
    const unsigned short* Bw = B + (size_t)(colBase + wave * 32 + sr) * ldb + sc;
    unsigned short* Asw = As + wave * 32 * BK;
    unsigned short* Bsw = Bs + wave * 32 * BK;

    int arow = (wr * 64 + (lane & 15)) * BK + (lane >> 4) * 8;
    int brow = (wc * 64 + (lane & 15)) * BK + (lane >> 4) * 8;

    for (int kt = 0; kt < K; kt += BK) {
        gl2lds16(Aw + kt, Asw);
        gl2lds16(Aw + kt + (size_t)16 * lda, Asw + 16 * BK);
        gl2lds16(Bw + kt, Bsw);
        gl2lds16(Bw + kt + (size_t)16 * ldb, Bsw + 16 * BK);
        __syncthreads();
        bf16x8 af[4], bfr[4];
#pragma unroll
        for (int i = 0; i < 4; ++i) af[i] = *(const bf16x8*)&As[arow + i * 16 * BK];
#pragma unroll
        for (int j = 0; j < 4; ++j) bfr[j] = *(const bf16x8*)&Bs[brow + j * 16 * BK];
#pragma unroll
        for (int i = 0; i < 4; ++i)
#pragma unroll
            for (int j = 0; j < 4; ++j)
                acc[i][j] = __builtin_amdgcn_mfma_f32_16x16x32_bf16(af[i], bfr[j], acc[i][j], 0, 0, 0);
        __syncthreads();
    }

    int r0 = rowBase + wr * 64 + ((lane >> 4) << 2);
    int c0 = colBase + wc * 64 + (lane & 15);
#pragma unroll
    for (int j = 0; j < 4; ++j) {
        int col = c0 + j * 16;
        float bv = bias ? bias[col] : 0.0f;
#pragma unroll
        for (int i = 0; i < 4; ++i) {
            int row = r0 + i * 16;
#pragma unroll
            for (int r = 0; r < 4; ++r) {
                float v = acc[i][j][r] + bv;
                if (ACT == 1) v = (v > 0.0f) ? (v + 1.0f) : __expf(v);
                if (OUT_BF16) ((unsigned short*)Cout)[(size_t)(row + r) * N + col] = f2bf(v);
                else          ((float*)Cout)[(size_t)(row + r) * N + col] = v;
            }
        }
    }
}

// ---------------------------------------------------------------- kv partial: kv[c][d] += v[l,c]*k[l,d] over an L-chunk
__global__ __launch_bounds__(256)
void kv_partial(const unsigned short* __restrict__ Kb, const unsigned short* __restrict__ Vb,
                float* __restrict__ kvp, float* __restrict__ ksp)
{
    int chunk = blockIdx.x;   // 0..31 (128 rows each)
    int g = blockIdx.y;       // 0..15 = b*8+hkv
    int b = g >> 3, hkv = g & 7;
    __shared__ float kl[32][128];
    __shared__ float vl[32][128];
    int tid = threadIdx.x;
    int c0 = (tid >> 4) * 8, d0 = (tid & 15) * 8;
    float acc[8][8] = {};
    float ksacc = 0.0f;
    size_t rowBase = (size_t)b * SEQ + (size_t)chunk * 128;

    for (int sch = 0; sch < 4; ++sch) {
        __syncthreads();
        for (int t = tid; t < 512; t += 256) {
            int l = t >> 4, col = (t & 15) * 8;
            size_t off = (rowBase + sch * 32 + l) * (NKV * HD) + hkv * HD + col;
            uint4 kr = *(const uint4*)(Kb + off);
            uint4 vr = *(const uint4*)(Vb + off);
            unsigned int ku[4] = {kr.x, kr.y, kr.z, kr.w};
            unsigned int vu[4] = {vr.x, vr.y, vr.z, vr.w};
#pragma unroll
            for (int q = 0; q < 4; ++q) {
                kl[l][col + q * 2]     = bf2f((unsigned short)(ku[q] & 0xffff));
                kl[l][col + q * 2 + 1] = bf2f((unsigned short)(ku[q] >> 16));
                vl[l][col + q * 2]     = bf2f((unsigned short)(vu[q] & 0xffff));
                vl[l][col + q * 2 + 1] = bf2f((unsigned short)(vu[q] >> 16));
            }
        }
        __syncthreads();
        for (int l = 0; l < 32; ++l) {
            float vv[8], kk[8];
#pragma unroll
            for (int x = 0; x < 8; ++x) { vv[x] = vl[l][c0 + x]; kk[x] = kl[l][d0 + x]; }
#pragma unroll
            for (int x = 0; x < 8; ++x)
#pragma unroll
                for (int y = 0; y < 8; ++y)
                    acc[x][y] += vv[x] * kk[y];
        }
        if (tid < 128) {
            for (int l = 0; l < 32; ++l) ksacc += kl[l][tid];
        }
    }
    float* out = kvp + ((size_t)g * 32 + chunk) * (HD * HD);
#pragma unroll
    for (int x = 0; x < 8; ++x)
#pragma unroll
        for (int y = 0; y < 8; ++y)
            out[(c0 + x) * HD + d0 + y] = acc[x][y];
    if (tid < 128) ksp[((size_t)g * 32 + chunk) * HD + tid] = ksacc;
}

// ---------------------------------------------------------------- reduce partials -> kv_bf16, ksum
__global__ __launch_bounds__(256)
void kv_reduce(const float* __restrict__ kvp, const float* __restrict__ ksp,
               unsigned short* __restrict__ kvb, float* __restrict__ ksum)
{
    int slice = blockIdx.x;  // 0..15
    int g = blockIdx.y;      // 0..15
    int tid = threadIdx.x;
    int e = slice * 1024 + tid * 4;
    float4 s = {0.f, 0.f, 0.f, 0.f};
    for (int ch = 0; ch < 32; ++ch) {
        float4 p = *(const float4*)(kvp + ((size_t)g * 32 + ch) * (HD * HD) + e);
        s.x += p.x; s.y += p.y; s.z += p.z; s.w += p.w;
    }
    ushort4 o;
    o.x = f2bf(s.x); o.y = f2bf(s.y); o.z = f2bf(s.z); o.w = f2bf(s.w);
    *(ushort4*)(kvb + (size_t)g * HD * HD + e) = o;
    if (slice == 0 && tid < 128) {
        float ss = 0.f;
        for (int ch = 0; ch < 32; ++ch) ss += ksp[((size_t)g * 32 + ch) * HD + tid];
        ksum[g * HD + tid] = ss;
    }
}

// ---------------------------------------------------------------- attn GEMM: per (row-tile, head): C = q @ kv^T, /(ksum+eps), bf16 out
__global__ __launch_bounds__(256)
void attn_gemm(const unsigned short* __restrict__ Q,
               const unsigned short* __restrict__ KV,
               const float* __restrict__ KS,
               unsigned short* __restrict__ Out)
{
    const int BK = 32;
    __shared__ unsigned short As[128 * BK];
    __shared__ unsigned short Bs[128 * BK];

    int rt = blockIdx.x;   // 0..63
    int h  = blockIdx.y;   // 0..31
    int g = (rt >> 5) * NKV + (h >> 2);
    int rowBase = rt << 7;

    const unsigned short* A = Q + (size_t)h * HD;           // lda = HIDDEN
    const unsigned short* B = KV + (size_t)g * HD * HD;     // ldb = HD
    const float* ks = KS + g * HD;

    int tid = threadIdx.x;
    int wave = tid >> 6, lane = tid & 63;
    int wr = wave >> 1, wc = wave & 1;

    f32x4 acc[4][4] = {};

    int sr = lane >> 2;
    int sc = (lane & 3) * 8;

    const unsigned short* Aw = A + (size_t)(rowBase + wave * 32 + sr) * HIDDEN + sc;
    const unsigned short* Bw = B + (size_t)(wave * 32 + sr) * HD + sc;
    unsigned short* Asw = As + wave * 32 * BK;
    unsigned short* Bsw = Bs + wave * 32 * BK;

    int arow = (wr * 64 + (lane & 15)) * BK + (lane >> 4) * 8;
    int brow = (wc * 64 + (lane & 15)) * BK + (lane >> 4) * 8;

    for (int kt = 0; kt < HD; kt += BK) {
        gl2lds16(Aw + kt, Asw);
        gl2lds16(Aw + kt + (size_t)16 * HIDDEN, Asw + 16 * BK);
        gl2lds16(Bw + kt, Bsw);
        gl2lds16(Bw + kt + (size_t)16 * HD, Bsw + 16 * BK);
        __syncthreads();
        bf16x8 af[4], bfr[4];
#pragma unroll
        for (int i = 0; i < 4; ++i) af[i] = *(const bf16x8*)&As[arow + i * 16 * BK];
#pragma unroll
        for (int j = 0; j < 4; ++j) bfr[j] = *(const bf16x8*)&Bs[brow + j * 16 * BK];
#pragma unroll
        for (int i = 0; i < 4; ++i)
#pragma unroll
            for (int j = 0; j < 4; ++j)
                acc[i][j] = __builtin_amdgcn_mfma_f32_16x16x32_bf16(af[i], bfr[j], acc[i][j], 0, 0, 0);
        __syncthreads();
    }

    int r0 = rowBase + wr * 64 + ((lane >> 4) << 2);
    int c0 = wc * 64 + (lane & 15);
#pragma unroll
    for (int j = 0; j < 4; ++j) {
        int col = c0 + j * 16;
        float inv = 1.0f / (ks[col] + 1e-10f);
#pragma unroll
        for (int i = 0; i < 4; ++i) {
            int row = r0 + i * 16;
#pragma unroll
            for (int r = 0; r < 4; ++r) {
                float v = acc[i][j][r] * inv;
                Out[(size_t)(row + r) * HIDDEN + h * HD + col] = f2bf(v);
            }
        }
    }
}

// ---------------------------------------------------------------- launch
extern "C" void kernel_launch(void* const* d_in, const int* in_sizes, int n_in,
                              void* d_out, int out_size, void* d_ws, size_t ws_size,
                              hipStream_t stream)
{
    const float* hs = (const float*)d_in[0];
    const float* Wq = (const float*)d_in[1];
    const float* bq = (const float*)d_in[2];
    const float* Wk = (const float*)d_in[3];
    const float* bk = (const float*)d_in[4];
    const float* Wv = (const float*)d_in[5];
    const float* bv = (const float*)d_in[6];
    const float* Wo = (const float*)d_in[7];
    const float* bo = (const float*)d_in[8];

    char* ws = (char*)d_ws;
    size_t off = 0;
    auto alloc = [&](size_t bytes) -> char* {
        char* p = ws + off;
        off += (bytes + 255) & ~(size_t)255;
        return p;
    };

    unsigned short* hs_b = (unsigned short*)alloc((size_t)ROWS * HIDDEN * 2);     // 67 MB (reused by attn)
    unsigned short* Wq_b = (unsigned short*)alloc((size_t)HIDDEN * HIDDEN * 2);   // 33.5 MB (reused by kvp)
    unsigned short* Wk_b = (unsigned short*)alloc((size_t)NKV * HD * HIDDEN * 2); // 8.4 MB
    unsigned short* Wv_b = (unsigned short*)alloc((size_t)NKV * HD * HIDDEN * 2); // 8.4 MB
    unsigned short* Wo_b = (unsigned short*)alloc((size_t)HIDDEN * HIDDEN * 2);   // 33.5 MB
    unsigned short* k_b  = (unsigned short*)alloc((size_t)ROWS * NKV * HD * 2);   // 16.8 MB
    unsigned short* v_b  = (unsigned short*)alloc((size_t)ROWS * NKV * HD * 2);   // 16.8 MB
    float* ksp   = (float*)alloc((size_t)16 * 32 * HD * 4);
    unsigned short* kvb = (unsigned short*)alloc((size_t)16 * HD * HD * 2);
    float* ksum  = (float*)alloc((size_t)16 * HD * 4);

    // aliases (lifetime-disjoint):
    float* kvp = (float*)Wq_b;                 // 33.5 MB partials, Wq dead after Q GEMM
    unsigned short* attn_b = hs_b;             // hs dead after V GEMM
    unsigned short* q_b = (unsigned short*)d_out; // 67 MB in 134 MB d_out, dead before final GEMM writes

    (void)in_sizes; (void)n_in; (void)out_size; (void)ws_size;

    auto cast = [&](const float* in, unsigned short* out, size_t n) {
        int n4 = (int)(n / 4);
        int blocks = (n4 + 255) / 256;
        if (blocks > 2048) blocks = 2048;
        cast_kernel<<<dim3(blocks), dim3(256), 0, stream>>>(in, out, n4);
    };

    cast(hs, hs_b, (size_t)ROWS * HIDDEN);
    cast(Wq, Wq_b, (size_t)HIDDEN * HIDDEN);
    cast(Wk, Wk_b, (size_t)NKV * HD * HIDDEN);
    cast(Wv, Wv_b, (size_t)NKV * HD * HIDDEN);
    cast(Wo, Wo_b, (size_t)HIDDEN * HIDDEN);

    // Q = phi(hs @ Wq^T + bq) -> bf16   [8192 x 4096]
    gemm_bt<1, 1><<<dim3(2048), dim3(256), 0, stream>>>(hs_b, HIDDEN, Wq_b, HIDDEN, bq, q_b, ROWS, HIDDEN, HIDDEN);
    // K = phi(hs @ Wk^T + bk) -> bf16   [8192 x 1024]
    gemm_bt<1, 1><<<dim3(512), dim3(256), 0, stream>>>(hs_b, HIDDEN, Wk_b, HIDDEN, bk, k_b, ROWS, NKV * HD, HIDDEN);
    // V = hs @ Wv^T + bv -> bf16        [8192 x 1024]
    gemm_bt<0, 1><<<dim3(512), dim3(256), 0, stream>>>(hs_b, HIDDEN, Wv_b, HIDDEN, bv, v_b, ROWS, NKV * HD, HIDDEN);

    // KV summary + ksum
    kv_partial<<<dim3(32, 16), dim3(256), 0, stream>>>(k_b, v_b, kvp, ksp);
    kv_reduce<<<dim3(16, 16), dim3(256), 0, stream>>>(kvp, ksp, kvb, ksum);

    // attn = (q @ kv^T) / (ksum + eps) -> bf16  [8192 x 4096]
    attn_gemm<<<dim3(64, 32), dim3(256), 0, stream>>>(q_b, kvb, ksum, attn_b);

    // out = attn @ Wo^T + bo -> f32
    gemm_bt<0, 0><<<dim3(2048), dim3(256), 0, stream>>>(attn_b, HIDDEN, Wo_b, HIDDEN, bo, d_out, ROWS, HIDDEN, HIDDEN);
}